// Round 15
// baseline (347.506 us; speedup 1.0000x reference)
//
#include <hip/hip_runtime.h>

// MultiLayerGCN on MI355X — round 15: R12 baseline (289us) + two independent
// fixes: (1) k_mlp hoisted W-chunk prefetch: global loads issued BEFORE the
// compute section (complete under MFMA), LDS write between barriers costs ~0
// wait. Unconditional reg arrays + __launch_bounds__(256,1) prevent the R6
// spill (compiler VGPR cap). (2) ELL counters padded to 1 per 128B line
// (stride 32 ints) — kills per-line atomic serialization in the fill.
// Math: agg1 = Anorm@x;  t2 = (relu(agg1@W1+b1))@W2      [k_mlp, H=512]
//       h2 = relu(Anorm@t2 + b2)
//       out = relu(relu(h2@W3+b3)@W4+b4)                 [k_mlp, H=1024]
// Anorm@y [d] = sum_{e: dst=d} nrm[e]*y[src(e)] + y[d]*dinv[d]^2

#define ELLW 64
#define CNTS 32   // counter stride in ints (128 B line)

typedef short bf16x8 __attribute__((ext_vector_type(8)));
typedef float f32x4 __attribute__((ext_vector_type(4)));

__device__ __forceinline__ unsigned short f2b(float f) {
    unsigned u = __builtin_bit_cast(unsigned, f);
    unsigned r = (u + 0x7FFFu + ((u >> 16) & 1u)) >> 16;
    return (unsigned short)r;
}
__device__ __forceinline__ float b2f(unsigned short u) {
    return __builtin_bit_cast(float, (unsigned)u << 16);
}

// merged setup: ELL fill (atomics, latency-bound) | weight transposes | x->bf16.
// Block ranges: [0,3125) fill, [3125,4405) weights, [4405,10655) x.
// cnt (padded, stride CNTS) must be zeroed before this kernel.
__global__ void k_setup(const float* __restrict__ x,
                        const float* __restrict__ W1, const float* __restrict__ W2,
                        const float* __restrict__ W3, const float* __restrict__ W4,
                        unsigned short* __restrict__ W1t, unsigned short* __restrict__ W2t,
                        unsigned short* __restrict__ W3t, unsigned short* __restrict__ W4t,
                        unsigned short* __restrict__ xb,
                        const int* __restrict__ src, const int* __restrict__ dst,
                        const float* __restrict__ ew, int* __restrict__ cnt,
                        int2* __restrict__ s_edge, int Nn, int E) {
    int b = blockIdx.x;
    if (b < 3125) {
        int e = b * 256 + threadIdx.x;
        if (e < E) {
            int d = dst[e];
            int2 rec = make_int2(src[e], __builtin_bit_cast(int, ew[e]));
            int slot = atomicAdd(&cnt[(size_t)d * CNTS], 1);
            if (slot < ELLW) s_edge[(size_t)d * ELLW + slot] = rec;
        }
    } else if (b < 4405) {
        int i = (b - 3125) * 256 + threadIdx.x;
        if (i < 65536) {                       // W1: 128x512
            int k = i >> 9, n = i & 511;
            W1t[n * 128 + k] = f2b(W1[i]);
        } else if (i < 131072) {               // W2: 512x128
            int j = i - 65536; int k = j >> 7, n = j & 127;
            W2t[n * 512 + k] = f2b(W2[j]);
        } else if (i < 262144) {               // W3: 128x1024
            int j = i - 131072; int k = j >> 10, n = j & 1023;
            W3t[n * 128 + k] = f2b(W3[j]);
        } else {                               // W4: 1024x64
            int j = i - 262144; int k = j >> 6, n = j & 63;
            W4t[n * 1024 + k] = f2b(W4[j]);
        }
    } else {
        int i = (b - 4405) * 256 + threadIdx.x;
        if (i < Nn * 32) {
            float4 v = ((const float4*)x)[i];
            ushort4 o;
            o.x = f2b(v.x); o.y = f2b(v.y); o.z = f2b(v.z); o.w = f2b(v.w);
            ((ushort4*)xb)[i] = o;
        }
    }
}

// one wave per node: dinv[node] = rsqrt(1 + sum_j w_j)   (no atomics)
__global__ __launch_bounds__(256) void k_deg(const int2* __restrict__ s_edge,
                                             const int* __restrict__ cnt,
                                             float* __restrict__ dinv, int Nn) {
    int node = blockIdx.x * 4 + (threadIdx.x >> 6);
    if (node >= Nn) return;
    int lane = threadIdx.x & 63;
    int c = min(cnt[(size_t)node * CNTS], ELLW);
    float s = 0.0f;
    if (lane < c) s = __builtin_bit_cast(float, s_edge[(size_t)node * ELLW + lane].y);
    #pragma unroll
    for (int d = 32; d > 0; d >>= 1) s += __shfl_down(s, d);
    if (lane == 0) dinv[node] = rsqrtf(1.0f + s);
}

// one wave per node; lane j<c holds edge j's (src, nrm) in regs, broadcast via shfl.
// FIRST: compute nrm = dinv[src]*w*dinv[node], write back into record.y.
template <bool FIRST, bool BIAS_RELU>
__global__ __launch_bounds__(256) void k_gather(
    const unsigned short* __restrict__ Xb, int2* __restrict__ s_edge,
    const int* __restrict__ cnt, const float* __restrict__ dinv,
    const float* __restrict__ bias, unsigned short* __restrict__ outb, int Nn) {
    int node = blockIdx.x * 4 + (threadIdx.x >> 6);
    if (node >= Nn) return;
    int lane = threadIdx.x & 63;
    float di = dinv[node];
    float dii = di * di;
    ushort2 sv = ((const ushort2*)(Xb + (size_t)node * 128))[lane];
    float ax = b2f(sv.x) * dii, ay = b2f(sv.y) * dii;

    int c = min(cnt[(size_t)node * CNTS], ELLW);
    size_t base = (size_t)node * ELLW;
    int sreg = 0;
    float nv = 0.0f;
    if (lane < c) {
        int2 rec = s_edge[base + lane];
        sreg = rec.x;
        if (FIRST) {
            float wv = __builtin_bit_cast(float, rec.y);
            nv = dinv[sreg] * wv * di;
            ((int*)s_edge)[2 * (base + lane) + 1] = __builtin_bit_cast(int, nv);
        } else {
            nv = __builtin_bit_cast(float, rec.y);
        }
    }

    int j = 0;
    for (; j + 8 <= c; j += 8) {
        int s0 = __shfl(sreg, j),     s1 = __shfl(sreg, j + 1);
        int s2 = __shfl(sreg, j + 2), s3 = __shfl(sreg, j + 3);
        int s4 = __shfl(sreg, j + 4), s5 = __shfl(sreg, j + 5);
        int s6 = __shfl(sreg, j + 6), s7 = __shfl(sreg, j + 7);
        float n0 = __shfl(nv, j),     n1 = __shfl(nv, j + 1);
        float n2 = __shfl(nv, j + 2), n3 = __shfl(nv, j + 3);
        float n4 = __shfl(nv, j + 4), n5 = __shfl(nv, j + 5);
        float n6 = __shfl(nv, j + 6), n7 = __shfl(nv, j + 7);
        ushort2 r0 = ((const ushort2*)(Xb + (size_t)s0 * 128))[lane];
        ushort2 r1 = ((const ushort2*)(Xb + (size_t)s1 * 128))[lane];
        ushort2 r2 = ((const ushort2*)(Xb + (size_t)s2 * 128))[lane];
        ushort2 r3 = ((const ushort2*)(Xb + (size_t)s3 * 128))[lane];
        ushort2 r4 = ((const ushort2*)(Xb + (size_t)s4 * 128))[lane];
        ushort2 r5 = ((const ushort2*)(Xb + (size_t)s5 * 128))[lane];
        ushort2 r6 = ((const ushort2*)(Xb + (size_t)s6 * 128))[lane];
        ushort2 r7 = ((const ushort2*)(Xb + (size_t)s7 * 128))[lane];
        ax += n0 * b2f(r0.x) + n1 * b2f(r1.x) + n2 * b2f(r2.x) + n3 * b2f(r3.x);
        ay += n0 * b2f(r0.y) + n1 * b2f(r1.y) + n2 * b2f(r2.y) + n3 * b2f(r3.y);
        ax += n4 * b2f(r4.x) + n5 * b2f(r5.x) + n6 * b2f(r6.x) + n7 * b2f(r7.x);
        ay += n4 * b2f(r4.y) + n5 * b2f(r5.y) + n6 * b2f(r6.y) + n7 * b2f(r7.y);
    }
    for (; j < c; ++j) {
        int sj = __shfl(sreg, j);
        float nj = __shfl(nv, j);
        ushort2 r = ((const ushort2*)(Xb + (size_t)sj * 128))[lane];
        ax += nj * b2f(r.x);
        ay += nj * b2f(r.y);
    }

    if (BIAS_RELU) {
        float2 bv = ((const float2*)bias)[lane];
        ax = fmaxf(ax + bv.x, 0.0f);
        ay = fmaxf(ay + bv.y, 0.0f);
    }
    ushort2 o; o.x = f2b(ax); o.y = f2b(ay);
    ((ushort2*)(outb + (size_t)node * 128))[lane] = o;
}

// Fused 2-layer MLP: out = g2(g1(A@Wh + bh) @ Wo [+ bo]), g1 = relu,
// g2 = relu iff HAS_BO. A: [M][128] bf16; Wht: [H][128]; Wot: [OUTW][H].
// 128 rows/block, 4 waves x 32 rows (R12 shape). HOISTED PREFETCH: W-chunk
// global loads are issued before the compute section (complete under MFMA);
// the barrier-bracketed LDS write then has ~0 vmcnt wait. Unconditional reg
// arrays + launch_bounds(256,1) so the compiler doesn't spill them (R6).
template <int H, int OUTW, bool HAS_BO, bool OUT_BF16>
__global__ __launch_bounds__(256, 1) void k_mlp(
    const unsigned short* __restrict__ A, const unsigned short* __restrict__ Wht,
    const unsigned short* __restrict__ Wot, const float* __restrict__ bh,
    const float* __restrict__ bo, void* __restrict__ out, int M) {
    constexpr int HC = H / 64;            // hidden chunks
    constexpr int NJ = OUTW / 16;         // out col tiles
    constexpr int OW4 = OUTW / 32;        // int4/thread for Wo chunk staging
    __shared__ __align__(16) unsigned short Whs[64 * 128];   // 16 KB
    __shared__ __align__(16) unsigned short Ps[128 * 64];    // 16 KB (wave-private rows)
    __shared__ __align__(16) unsigned short Wos[OUTW * 64];  // 8/16 KB
    const int tid = threadIdx.x, wave = tid >> 6, lane = tid & 63;
    const int lm = lane & 15, quad = lane >> 4;
    const int bm0 = blockIdx.x * 128;

    // A-fragments in registers (read once): 2 row-tiles of 16
    bf16x8 af[2][4];
    #pragma unroll
    for (int i = 0; i < 2; ++i) {
        int gr = bm0 + wave * 32 + i * 16 + lm;
        #pragma unroll
        for (int kb = 0; kb < 4; ++kb) af[i][kb] = bf16x8{0, 0, 0, 0, 0, 0, 0, 0};
        if (gr < M) {
            #pragma unroll
            for (int kb = 0; kb < 4; ++kb)
                af[i][kb] = *(const bf16x8*)(A + (size_t)gr * 128 + kb * 32 + quad * 8);
        }
    }

    // prefetch regs for chunk 0
    int4 pw[4], po[OW4];
    #pragma unroll
    for (int u = 0; u < 4; ++u) {
        int idx = tid + u * 256; int r = idx >> 4, g = idx & 15;
        pw[u] = *(const int4*)(Wht + (size_t)r * 128 + g * 8);
    }
    #pragma unroll
    for (int u = 0; u < OW4; ++u) {
        int idx = tid + u * 256; int r = idx >> 3, g = idx & 7;
        po[u] = *(const int4*)(Wot + (size_t)r * H + g * 8);
    }

    f32x4 oacc[2][NJ] = {};
    for (int c = 0; c < HC; ++c) {
        if (c) __syncthreads();   // all waves done reading Whs/Wos of chunk c-1
        // dump prefetched regs -> LDS (loads completed during prior compute)
        #pragma unroll
        for (int u = 0; u < 4; ++u) {
            int idx = tid + u * 256; int r = idx >> 4, g = idx & 15;
            *(int4*)&Whs[r * 128 + ((g ^ (r & 15)) * 8)] = pw[u];
        }
        #pragma unroll
        for (int u = 0; u < OW4; ++u) {
            int idx = tid + u * 256; int r = idx >> 3, g = idx & 7;
            *(int4*)&Wos[r * 64 + ((g ^ (r & 7)) * 8)] = po[u];
        }
        __syncthreads();          // staging visible

        // issue next chunk's loads now — they complete under the MFMA below
        const int cn = (c + 1 < HC) ? c + 1 : 0;   // clamped (last iter harmless)
        #pragma unroll
        for (int u = 0; u < 4; ++u) {
            int idx = tid + u * 256; int r = idx >> 4, g = idx & 15;
            pw[u] = *(const int4*)(Wht + (size_t)(cn * 64 + r) * 128 + g * 8);
        }
        #pragma unroll
        for (int u = 0; u < OW4; ++u) {
            int idx = tid + u * 256; int r = idx >> 3, g = idx & 7;
            po[u] = *(const int4*)(Wot + (size_t)r * H + cn * 64 + g * 8);
        }

        // GEMM-h: 32 rows x 64 hidden cols (16 ds_read -> 32 MFMA)
        f32x4 hacc[2][4] = {};
        #pragma unroll
        for (int kb = 0; kb < 4; ++kb) {
            bf16x8 bfr[4];
            #pragma unroll
            for (int j = 0; j < 4; ++j) {
                int r = j * 16 + lm, g = kb * 4 + quad;
                bfr[j] = *(const bf16x8*)&Whs[r * 128 + ((g ^ (r & 15)) * 8)];
            }
            #pragma unroll
            for (int i = 0; i < 2; ++i)
                #pragma unroll
                for (int j = 0; j < 4; ++j)
                    hacc[i][j] = __builtin_amdgcn_mfma_f32_16x16x32_bf16(
                        af[i][kb], bfr[j], hacc[i][j], 0, 0, 0);
        }

        // epilogue -> Ps (wave-private rows; no barrier needed)
        #pragma unroll
        for (int i = 0; i < 2; ++i) {
            #pragma unroll
            for (int j = 0; j < 4; ++j) {
                int col = j * 16 + lm;
                float bv = bh[c * 64 + col];
                #pragma unroll
                for (int r4 = 0; r4 < 4; ++r4) {
                    int row = wave * 32 + i * 16 + quad * 4 + r4;
                    float o = fmaxf(hacc[i][j][r4] + bv, 0.0f);
                    Ps[row * 64 + (((col >> 3) ^ (row & 7)) * 8) + (col & 7)] = f2b(o);
                }
            }
        }

        // GEMM-o: accumulate 32 rows x OUTW cols from staged Wos
        #pragma unroll
        for (int kb = 0; kb < 2; ++kb) {
            bf16x8 pf[2];
            #pragma unroll
            for (int i = 0; i < 2; ++i) {
                int r = wave * 32 + i * 16 + lm, g = kb * 4 + quad;
                pf[i] = *(const bf16x8*)&Ps[r * 64 + ((g ^ (r & 7)) * 8)];
            }
            #pragma unroll
            for (int j = 0; j < NJ; ++j) {
                int r = j * 16 + lm, g = kb * 4 + quad;
                bf16x8 wf = *(const bf16x8*)&Wos[r * 64 + ((g ^ (r & 7)) * 8)];
                #pragma unroll
                for (int i = 0; i < 2; ++i)
                    oacc[i][j] = __builtin_amdgcn_mfma_f32_16x16x32_bf16(
                        pf[i], wf, oacc[i][j], 0, 0, 0);
            }
        }
    }

    // final epilogue
    #pragma unroll
    for (int i = 0; i < 2; ++i) {
        #pragma unroll
        for (int j = 0; j < NJ; ++j) {
            int col = j * 16 + lm;
            float bv = HAS_BO ? bo[col] : 0.0f;
            #pragma unroll
            for (int r4 = 0; r4 < 4; ++r4) {
                int m = bm0 + wave * 32 + i * 16 + quad * 4 + r4;
                if (m < M) {
                    float o = oacc[i][j][r4];
                    if (HAS_BO) o = fmaxf(o + bv, 0.0f);
                    if (OUT_BF16)
                        ((unsigned short*)out)[(size_t)m * OUTW + col] = f2b(o);
                    else
                        ((float*)out)[(size_t)m * OUTW + col] = o;
                }
            }
        }
    }
}

static inline int cdiv(long a, long b) { return (int)((a + b - 1) / b); }

extern "C" void kernel_launch(void* const* d_in, const int* in_sizes, int n_in,
                              void* d_out, int out_size, void* d_ws, size_t ws_size,
                              hipStream_t stream) {
    const float* x  = (const float*)d_in[0];
    const int*   ei = (const int*)d_in[1];
    const float* ew = (const float*)d_in[2];
    const float* W1 = (const float*)d_in[3];
    const float* b1 = (const float*)d_in[4];
    const float* W2 = (const float*)d_in[5];
    const float* b2 = (const float*)d_in[6];
    const float* W3 = (const float*)d_in[7];
    const float* b3 = (const float*)d_in[8];
    const float* W4 = (const float*)d_in[9];
    const float* b4 = (const float*)d_in[10];
    const int Nn = in_sizes[0] / 128;   // 50000
    const int E  = in_sizes[1] / 2;     // 800000
    const int* src = ei;
    const int* dst = ei + E;

    char* ws = (char*)d_ws;
    size_t off_b = 0;
    auto alloc = [&](size_t bytes) -> void* {
        void* p = ws + off_b;
        off_b += (bytes + 255) & ~(size_t)255;
        return p;
    };
    float*          dinv   = (float*)alloc((size_t)Nn * 4);
    int*            cnt    = (int*)alloc((size_t)Nn * CNTS * 4);     // padded counters
    int2*           s_edge = (int2*)alloc((size_t)Nn * ELLW * 8);    // 25.6 MB, (src, w->nrm)
    unsigned short* W1t    = (unsigned short*)alloc(512 * 128 * 2);
    unsigned short* W2t    = (unsigned short*)alloc(128 * 512 * 2);
    unsigned short* W3t    = (unsigned short*)alloc(1024 * 128 * 2);
    unsigned short* W4t    = (unsigned short*)alloc(64 * 1024 * 2);
    unsigned short* xb     = (unsigned short*)alloc((size_t)Nn * 128 * 2);
    unsigned short* t2b    = (unsigned short*)alloc((size_t)Nn * 128 * 2);
    unsigned short* actb   = (unsigned short*)alloc((size_t)Nn * 128 * 2);
    float*          out    = (float*)d_out;

    // zero padded ELL counters, then merged setup (fill_ell | weights | x->bf16)
    hipMemsetAsync(cnt, 0, (size_t)Nn * CNTS * 4, stream);
    k_setup<<<10655, 256, 0, stream>>>(x, W1, W2, W3, W4, W1t, W2t, W3t, W4t,
                                       xb, src, dst, ew, cnt, s_edge, Nn, E);
    k_deg<<<cdiv(Nn, 4), 256, 0, stream>>>(s_edge, cnt, dinv, Nn);

    // agg1 = Anorm@x (computes+stores nrm), fused layers 1+2 -> t2 (bf16)
    k_gather<true, false><<<cdiv(Nn, 4), 256, 0, stream>>>(
        xb, s_edge, cnt, dinv, nullptr, actb, Nn);
    k_mlp<512, 128, false, true><<<cdiv(Nn, 128), 256, 0, stream>>>(
        actb, W1t, W2t, b1, nullptr, t2b, Nn);

    // h2 = relu(Anorm@t2 + b2)
    k_gather<false, true><<<cdiv(Nn, 4), 256, 0, stream>>>(
        t2b, s_edge, cnt, dinv, b2, actb, Nn);

    // fused layers 3+4 -> out (fp32)
    k_mlp<1024, 64, true, false><<<cdiv(Nn, 128), 256, 0, stream>>>(
        actb, W3t, W4t, b3, b4, out, Nn);
}

// Round 16
// 287.213 us; speedup vs baseline: 1.2099x; 1.2099x over previous
//
#include <hip/hip_runtime.h>

// MultiLayerGCN on MI355X — round 16: R12 baseline (289us, proven) + packed
// 64-bit counter atomic (slot | fixed-point sum-of-w, R13-validated numerics)
// padded to one counter per 128B line, and elementwise k_deg (no ELL reads).
// mlp/gather/setup structure byte-identical to R12; R13/R14/R15 perturbations
// (prescale, col-split, reg-prefetch) all reverted — each measured a loss.
// Math: agg1 = Anorm@x;  t2 = (relu(agg1@W1+b1))@W2      [k_mlp, H=512]
//       h2 = relu(Anorm@t2 + b2)
//       out = relu(relu(h2@W3+b3)@W4+b4)                 [k_mlp, H=1024]
// Anorm@y [d] = sum_{e: dst=d} nrm[e]*y[src(e)] + y[d]*dinv[d]^2

#define ELLW 64
#define C64S 16   // cnt64 stride in u64 (128 B line per counter)

typedef short bf16x8 __attribute__((ext_vector_type(8)));
typedef float f32x4 __attribute__((ext_vector_type(4)));

__device__ __forceinline__ unsigned short f2b(float f) {
    unsigned u = __builtin_bit_cast(unsigned, f);
    unsigned r = (u + 0x7FFFu + ((u >> 16) & 1u)) >> 16;
    return (unsigned short)r;
}
__device__ __forceinline__ float b2f(unsigned short u) {
    return __builtin_bit_cast(float, (unsigned)u << 16);
}

// merged setup: ELL fill (1 packed 64b atomic/edge) | weight transposes | x->bf16.
// Block ranges: [0,3125) fill, [3125,4405) weights, [4405,10655) x.
// cnt64 (stride C64S) must be zeroed before this kernel.
__global__ void k_setup(const float* __restrict__ x,
                        const float* __restrict__ W1, const float* __restrict__ W2,
                        const float* __restrict__ W3, const float* __restrict__ W4,
                        unsigned short* __restrict__ W1t, unsigned short* __restrict__ W2t,
                        unsigned short* __restrict__ W3t, unsigned short* __restrict__ W4t,
                        unsigned short* __restrict__ xb,
                        const int* __restrict__ src, const int* __restrict__ dst,
                        const float* __restrict__ ew,
                        unsigned long long* __restrict__ cnt64,
                        int2* __restrict__ s_edge, int Nn, int E) {
    int b = blockIdx.x;
    if (b < 3125) {
        int e = b * 256 + threadIdx.x;
        if (e < E) {
            int d = dst[e];
            float wv = ew[e];
            unsigned wfix = (unsigned)(wv * 8388608.0f);   // 2^23 fixed point
            unsigned long long add = ((unsigned long long)1 << 32) | wfix;
            unsigned long long old = atomicAdd(&cnt64[(size_t)d * C64S], add);
            int slot = (int)(old >> 32);
            if (slot < ELLW)
                s_edge[(size_t)d * ELLW + slot] =
                    make_int2(src[e], __builtin_bit_cast(int, wv));
        }
    } else if (b < 4405) {
        int i = (b - 3125) * 256 + threadIdx.x;
        if (i < 65536) {                       // W1: 128x512
            int k = i >> 9, n = i & 511;
            W1t[n * 128 + k] = f2b(W1[i]);
        } else if (i < 131072) {               // W2: 512x128
            int j = i - 65536; int k = j >> 7, n = j & 127;
            W2t[n * 512 + k] = f2b(W2[j]);
        } else if (i < 262144) {               // W3: 128x1024
            int j = i - 131072; int k = j >> 10, n = j & 1023;
            W3t[n * 128 + k] = f2b(W3[j]);
        } else {                               // W4: 1024x64
            int j = i - 262144; int k = j >> 6, n = j & 63;
            W4t[n * 1024 + k] = f2b(W4[j]);
        }
    } else {
        int i = (b - 4405) * 256 + threadIdx.x;
        if (i < Nn * 32) {
            float4 v = ((const float4*)x)[i];
            ushort4 o;
            o.x = f2b(v.x); o.y = f2b(v.y); o.z = f2b(v.z); o.w = f2b(v.w);
            ((ushort4*)xb)[i] = o;
        }
    }
}

// elementwise: dinv[node] = rsqrt(1 + fixsum(cnt64)) — no ELL row reads
__global__ void k_deg(const unsigned long long* __restrict__ cnt64,
                      float* __restrict__ dinv, int Nn) {
    int i = blockIdx.x * 256 + threadIdx.x;
    if (i >= Nn) return;
    unsigned long long cv = cnt64[(size_t)i * C64S];
    float deg = 1.0f + (float)(unsigned)(cv & 0xFFFFFFFFull) * (1.0f / 8388608.0f);
    dinv[i] = rsqrtf(deg);
}

// one wave per node; lane j<c holds edge j's (src, nrm) in regs, broadcast via shfl.
// FIRST: compute nrm = dinv[src]*w*dinv[node], write back into record.y.
template <bool FIRST, bool BIAS_RELU>
__global__ __launch_bounds__(256) void k_gather(
    const unsigned short* __restrict__ Xb, int2* __restrict__ s_edge,
    const unsigned long long* __restrict__ cnt64, const float* __restrict__ dinv,
    const float* __restrict__ bias, unsigned short* __restrict__ outb, int Nn) {
    int node = blockIdx.x * 4 + (threadIdx.x >> 6);
    if (node >= Nn) return;
    int lane = threadIdx.x & 63;
    float di = dinv[node];
    float dii = di * di;
    ushort2 sv = ((const ushort2*)(Xb + (size_t)node * 128))[lane];
    float ax = b2f(sv.x) * dii, ay = b2f(sv.y) * dii;

    int c = min((int)(cnt64[(size_t)node * C64S] >> 32), ELLW);
    size_t base = (size_t)node * ELLW;
    int sreg = 0;
    float nv = 0.0f;
    if (lane < c) {
        int2 rec = s_edge[base + lane];
        sreg = rec.x;
        if (FIRST) {
            float wv = __builtin_bit_cast(float, rec.y);
            nv = dinv[sreg] * wv * di;
            ((int*)s_edge)[2 * (base + lane) + 1] = __builtin_bit_cast(int, nv);
        } else {
            nv = __builtin_bit_cast(float, rec.y);
        }
    }

    int j = 0;
    for (; j + 8 <= c; j += 8) {
        int s0 = __shfl(sreg, j),     s1 = __shfl(sreg, j + 1);
        int s2 = __shfl(sreg, j + 2), s3 = __shfl(sreg, j + 3);
        int s4 = __shfl(sreg, j + 4), s5 = __shfl(sreg, j + 5);
        int s6 = __shfl(sreg, j + 6), s7 = __shfl(sreg, j + 7);
        float n0 = __shfl(nv, j),     n1 = __shfl(nv, j + 1);
        float n2 = __shfl(nv, j + 2), n3 = __shfl(nv, j + 3);
        float n4 = __shfl(nv, j + 4), n5 = __shfl(nv, j + 5);
        float n6 = __shfl(nv, j + 6), n7 = __shfl(nv, j + 7);
        ushort2 r0 = ((const ushort2*)(Xb + (size_t)s0 * 128))[lane];
        ushort2 r1 = ((const ushort2*)(Xb + (size_t)s1 * 128))[lane];
        ushort2 r2 = ((const ushort2*)(Xb + (size_t)s2 * 128))[lane];
        ushort2 r3 = ((const ushort2*)(Xb + (size_t)s3 * 128))[lane];
        ushort2 r4 = ((const ushort2*)(Xb + (size_t)s4 * 128))[lane];
        ushort2 r5 = ((const ushort2*)(Xb + (size_t)s5 * 128))[lane];
        ushort2 r6 = ((const ushort2*)(Xb + (size_t)s6 * 128))[lane];
        ushort2 r7 = ((const ushort2*)(Xb + (size_t)s7 * 128))[lane];
        ax += n0 * b2f(r0.x) + n1 * b2f(r1.x) + n2 * b2f(r2.x) + n3 * b2f(r3.x);
        ay += n0 * b2f(r0.y) + n1 * b2f(r1.y) + n2 * b2f(r2.y) + n3 * b2f(r3.y);
        ax += n4 * b2f(r4.x) + n5 * b2f(r5.x) + n6 * b2f(r6.x) + n7 * b2f(r7.x);
        ay += n4 * b2f(r4.y) + n5 * b2f(r5.y) + n6 * b2f(r6.y) + n7 * b2f(r7.y);
    }
    for (; j < c; ++j) {
        int sj = __shfl(sreg, j);
        float nj = __shfl(nv, j);
        ushort2 r = ((const ushort2*)(Xb + (size_t)sj * 128))[lane];
        ax += nj * b2f(r.x);
        ay += nj * b2f(r.y);
    }

    if (BIAS_RELU) {
        float2 bv = ((const float2*)bias)[lane];
        ax = fmaxf(ax + bv.x, 0.0f);
        ay = fmaxf(ay + bv.y, 0.0f);
    }
    ushort2 o; o.x = f2b(ax); o.y = f2b(ay);
    ((ushort2*)(outb + (size_t)node * 128))[lane] = o;
}

// Fused 2-layer MLP (R12, proven): out = g2(g1(A@Wh + bh) @ Wo [+ bo]).
// 128 rows/block, 4 waves x 32 rows (16 Whs ds_reads feed 32 MFMA).
// A-frags in regs; Wh + Wo chunks staged in LDS, 2 barriers/chunk.
// P wave-private in LDS. XOR-swizzle: 2-way max (free).
template <int H, int OUTW, bool HAS_BO, bool OUT_BF16>
__global__ __launch_bounds__(256) void k_mlp(
    const unsigned short* __restrict__ A, const unsigned short* __restrict__ Wht,
    const unsigned short* __restrict__ Wot, const float* __restrict__ bh,
    const float* __restrict__ bo, void* __restrict__ out, int M) {
    constexpr int HC = H / 64;            // hidden chunks
    constexpr int NJ = OUTW / 16;         // out col tiles
    constexpr int OW4 = OUTW / 32;        // int4/thread for Wo chunk staging
    __shared__ __align__(16) unsigned short Whs[64 * 128];   // 16 KB
    __shared__ __align__(16) unsigned short Ps[128 * 64];    // 16 KB (wave-private rows)
    __shared__ __align__(16) unsigned short Wos[OUTW * 64];  // 8/16 KB
    const int tid = threadIdx.x, wave = tid >> 6, lane = tid & 63;
    const int lm = lane & 15, quad = lane >> 4;
    const int bm0 = blockIdx.x * 128;

    // A-fragments in registers (read once): 2 row-tiles of 16
    bf16x8 af[2][4];
    #pragma unroll
    for (int i = 0; i < 2; ++i) {
        int gr = bm0 + wave * 32 + i * 16 + lm;
        #pragma unroll
        for (int kb = 0; kb < 4; ++kb) af[i][kb] = bf16x8{0, 0, 0, 0, 0, 0, 0, 0};
        if (gr < M) {
            #pragma unroll
            for (int kb = 0; kb < 4; ++kb)
                af[i][kb] = *(const bf16x8*)(A + (size_t)gr * 128 + kb * 32 + quad * 8);
        }
    }

    // stage chunk 0 (Wh + Wo)
    #pragma unroll
    for (int u = 0; u < 4; ++u) {
        int idx = tid + u * 256; int r = idx >> 4, g = idx & 15;
        *(int4*)&Whs[r * 128 + ((g ^ (r & 15)) * 8)] =
            *(const int4*)(Wht + (size_t)r * 128 + g * 8);
    }
    #pragma unroll
    for (int u = 0; u < OW4; ++u) {
        int idx = tid + u * 256; int r = idx >> 3, g = idx & 7;
        *(int4*)&Wos[r * 64 + ((g ^ (r & 7)) * 8)] =
            *(const int4*)(Wot + (size_t)r * H + g * 8);
    }
    __syncthreads();

    f32x4 oacc[2][NJ] = {};
    for (int c = 0; c < HC; ++c) {
        // GEMM-h: 32 rows x 64 hidden cols (16 ds_read -> 32 MFMA)
        f32x4 hacc[2][4] = {};
        #pragma unroll
        for (int kb = 0; kb < 4; ++kb) {
            bf16x8 bfr[4];
            #pragma unroll
            for (int j = 0; j < 4; ++j) {
                int r = j * 16 + lm, g = kb * 4 + quad;
                bfr[j] = *(const bf16x8*)&Whs[r * 128 + ((g ^ (r & 15)) * 8)];
            }
            #pragma unroll
            for (int i = 0; i < 2; ++i)
                #pragma unroll
                for (int j = 0; j < 4; ++j)
                    hacc[i][j] = __builtin_amdgcn_mfma_f32_16x16x32_bf16(
                        af[i][kb], bfr[j], hacc[i][j], 0, 0, 0);
        }

        // epilogue -> Ps (wave-private rows; no barrier needed)
        #pragma unroll
        for (int i = 0; i < 2; ++i) {
            #pragma unroll
            for (int j = 0; j < 4; ++j) {
                int col = j * 16 + lm;
                float bv = bh[c * 64 + col];
                #pragma unroll
                for (int r4 = 0; r4 < 4; ++r4) {
                    int row = wave * 32 + i * 16 + quad * 4 + r4;
                    float o = fmaxf(hacc[i][j][r4] + bv, 0.0f);
                    Ps[row * 64 + (((col >> 3) ^ (row & 7)) * 8) + (col & 7)] = f2b(o);
                }
            }
        }

        // GEMM-o: accumulate 32 rows x OUTW cols from staged Wos
        #pragma unroll
        for (int kb = 0; kb < 2; ++kb) {
            bf16x8 pf[2];
            #pragma unroll
            for (int i = 0; i < 2; ++i) {
                int r = wave * 32 + i * 16 + lm, g = kb * 4 + quad;
                pf[i] = *(const bf16x8*)&Ps[r * 64 + ((g ^ (r & 7)) * 8)];
            }
            #pragma unroll
            for (int j = 0; j < NJ; ++j) {
                int r = j * 16 + lm, g = kb * 4 + quad;
                bf16x8 wf = *(const bf16x8*)&Wos[r * 64 + ((g ^ (r & 7)) * 8)];
                #pragma unroll
                for (int i = 0; i < 2; ++i)
                    oacc[i][j] = __builtin_amdgcn_mfma_f32_16x16x32_bf16(
                        pf[i], wf, oacc[i][j], 0, 0, 0);
            }
        }

        if (c + 1 < HC) {
            __syncthreads();   // all waves done reading Whs/Wos
            #pragma unroll
            for (int u = 0; u < 4; ++u) {
                int idx = tid + u * 256; int r = idx >> 4, g = idx & 15;
                *(int4*)&Whs[r * 128 + ((g ^ (r & 15)) * 8)] =
                    *(const int4*)(Wht + (size_t)((c + 1) * 64 + r) * 128 + g * 8);
            }
            #pragma unroll
            for (int u = 0; u < OW4; ++u) {
                int idx = tid + u * 256; int r = idx >> 3, g = idx & 7;
                *(int4*)&Wos[r * 64 + ((g ^ (r & 7)) * 8)] =
                    *(const int4*)(Wot + (size_t)r * H + (c + 1) * 64 + g * 8);
            }
            __syncthreads();   // staging visible before next chunk's reads
        }
    }

    // final epilogue
    #pragma unroll
    for (int i = 0; i < 2; ++i) {
        #pragma unroll
        for (int j = 0; j < NJ; ++j) {
            int col = j * 16 + lm;
            float bv = HAS_BO ? bo[col] : 0.0f;
            #pragma unroll
            for (int r4 = 0; r4 < 4; ++r4) {
                int m = bm0 + wave * 32 + i * 16 + quad * 4 + r4;
                if (m < M) {
                    float o = oacc[i][j][r4];
                    if (HAS_BO) o = fmaxf(o + bv, 0.0f);
                    if (OUT_BF16)
                        ((unsigned short*)out)[(size_t)m * OUTW + col] = f2b(o);
                    else
                        ((float*)out)[(size_t)m * OUTW + col] = o;
                }
            }
        }
    }
}

static inline int cdiv(long a, long b) { return (int)((a + b - 1) / b); }

extern "C" void kernel_launch(void* const* d_in, const int* in_sizes, int n_in,
                              void* d_out, int out_size, void* d_ws, size_t ws_size,
                              hipStream_t stream) {
    const float* x  = (const float*)d_in[0];
    const int*   ei = (const int*)d_in[1];
    const float* ew = (const float*)d_in[2];
    const float* W1 = (const float*)d_in[3];
    const float* b1 = (const float*)d_in[4];
    const float* W2 = (const float*)d_in[5];
    const float* b2 = (const float*)d_in[6];
    const float* W3 = (const float*)d_in[7];
    const float* b3 = (const float*)d_in[8];
    const float* W4 = (const float*)d_in[9];
    const float* b4 = (const float*)d_in[10];
    const int Nn = in_sizes[0] / 128;   // 50000
    const int E  = in_sizes[1] / 2;     // 800000
    const int* src = ei;
    const int* dst = ei + E;

    char* ws = (char*)d_ws;
    size_t off_b = 0;
    auto alloc = [&](size_t bytes) -> void* {
        void* p = ws + off_b;
        off_b += (bytes + 255) & ~(size_t)255;
        return p;
    };
    float*              dinv   = (float*)alloc((size_t)Nn * 4);
    unsigned long long* cnt64  = (unsigned long long*)alloc((size_t)Nn * C64S * 8);
    int2*               s_edge = (int2*)alloc((size_t)Nn * ELLW * 8);  // 25.6 MB
    unsigned short*     W1t    = (unsigned short*)alloc(512 * 128 * 2);
    unsigned short*     W2t    = (unsigned short*)alloc(128 * 512 * 2);
    unsigned short*     W3t    = (unsigned short*)alloc(1024 * 128 * 2);
    unsigned short*     W4t    = (unsigned short*)alloc(64 * 1024 * 2);
    unsigned short*     xb     = (unsigned short*)alloc((size_t)Nn * 128 * 2);
    unsigned short*     t2b    = (unsigned short*)alloc((size_t)Nn * 128 * 2);
    unsigned short*     actb   = (unsigned short*)alloc((size_t)Nn * 128 * 2);
    float*              out    = (float*)d_out;

    // zero padded packed counters, then merged setup (fill | weights | x->bf16)
    hipMemsetAsync(cnt64, 0, (size_t)Nn * C64S * 8, stream);
    k_setup<<<10655, 256, 0, stream>>>(x, W1, W2, W3, W4, W1t, W2t, W3t, W4t,
                                       xb, src, dst, ew, cnt64, s_edge, Nn, E);
    k_deg<<<cdiv(Nn, 256), 256, 0, stream>>>(cnt64, dinv, Nn);

    // agg1 = Anorm@x (computes+stores nrm), fused layers 1+2 -> t2 (bf16)
    k_gather<true, false><<<cdiv(Nn, 4), 256, 0, stream>>>(
        xb, s_edge, cnt64, dinv, nullptr, actb, Nn);
    k_mlp<512, 128, false, true><<<cdiv(Nn, 128), 256, 0, stream>>>(
        actb, W1t, W2t, b1, nullptr, t2b, Nn);

    // h2 = relu(Anorm@t2 + b2)
    k_gather<false, true><<<cdiv(Nn, 4), 256, 0, stream>>>(
        t2b, s_edge, cnt64, dinv, b2, actb, Nn);

    // fused layers 3+4 -> out (fp32)
    k_mlp<1024, 64, true, false><<<cdiv(Nn, 128), 256, 0, stream>>>(
        actb, W3t, W4t, b3, b4, out, Nn);
}